// Round 1
// baseline (3563.287 us; speedup 1.0000x reference)
//
#include <hip/hip_runtime.h>
#include <hip/hip_fp16.h>

#define N 8192
#define DK 256
#define LOG_N 9.0109133f   // ln(8192)

typedef unsigned short u16;
typedef u16   ushort8 __attribute__((ext_vector_type(8)));
typedef __bf16 bf16x8 __attribute__((ext_vector_type(8)));
typedef float  f32x4  __attribute__((ext_vector_type(4)));

__device__ __forceinline__ u16 f2bf(float f){
  unsigned u = __builtin_bit_cast(unsigned, f);
  return (u16)((u + 0x7fffu + ((u >> 16) & 1u)) >> 16);   // RNE fp32->bf16
}
__device__ __forceinline__ float h2f(u16 h){
  return __half2float(__ushort_as_half(h));
}

// ---------------------------------------------------------------------------
// prep: row sum-of-squares (fp32, from original inputs) + bf16 copies of x,y
// + init gt = -y2  (g0 = 0).  One wave per row; 16384 rows total.
// ---------------------------------------------------------------------------
__global__ __launch_bounds__(256) void prep_k(const float* __restrict__ x, const float* __restrict__ y,
                                              u16* __restrict__ xb, u16* __restrict__ yb,
                                              float* __restrict__ x2, float* __restrict__ y2,
                                              float* __restrict__ gt){
  const int w = threadIdx.x >> 6, l = threadIdx.x & 63;
  const int r = blockIdx.x * 4 + w;         // 0..16383
  const bool isx = r < N;
  const int rr = isx ? r : r - N;
  const float* src = (isx ? x : y) + (size_t)rr * DK;
  float4 v = *(const float4*)(src + l * 4);
  ushort4 bv;
  bv.x = f2bf(v.x); bv.y = f2bf(v.y); bv.z = f2bf(v.z); bv.w = f2bf(v.w);
  *(ushort4*)((isx ? xb : yb) + (size_t)rr * DK + l * 4) = bv;
  float p = v.x*v.x + v.y*v.y + v.z*v.z + v.w*v.w;
  #pragma unroll
  for (int off = 32; off > 0; off >>= 1) p += __shfl_down(p, off);
  if (l == 0){
    if (isx) x2[rr] = p;
    else { y2[rr] = p; gt[rr] = -p; }
  }
}

// ---------------------------------------------------------------------------
// gemm: z = xb * yb^T  (bf16 MFMA, fp32 acc), store fp16.
// 128x128 tile, 4 waves (2x2 of 64x64), BK=64 staged in LDS (pad +8 shorts
// per row -> 2-way-only bank aliasing on ds_read_b128, which is free).
// k-layout of A/B fragments is irrelevant (same mapping both operands,
// dot is permutation-invariant); C/D layout per m89: col=l&15, row=(l>>4)*4+reg.
// ---------------------------------------------------------------------------
__global__ __launch_bounds__(256) void gemm_k(const u16* __restrict__ xb, const u16* __restrict__ yb,
                                              u16* __restrict__ zp){
  __shared__ u16 As[128 * 72];
  __shared__ u16 Bs[128 * 72];
  const int t = threadIdx.x;
  const int w = t >> 6, l = t & 63;
  const int wm = w >> 1, wn = w & 1;
  const int brow = blockIdx.y * 128, bcol = blockIdx.x * 128;
  const int tr = t >> 3, tc = t & 7;
  f32x4 acc[4][4] = {};
  for (int ks = 0; ks < 4; ++ks){
    #pragma unroll
    for (int rr = 0; rr < 4; ++rr){
      const int row = tr + rr * 32;
      *(ushort8*)&As[row * 72 + tc * 8] = *(const ushort8*)&xb[(size_t)(brow + row) * DK + ks * 64 + tc * 8];
      *(ushort8*)&Bs[row * 72 + tc * 8] = *(const ushort8*)&yb[(size_t)(bcol + row) * DK + ks * 64 + tc * 8];
    }
    __syncthreads();
    #pragma unroll
    for (int kk = 0; kk < 2; ++kk){
      bf16x8 av[4], bv[4];
      #pragma unroll
      for (int mi = 0; mi < 4; ++mi){
        const int ar = wm * 64 + mi * 16 + (l & 15);
        av[mi] = __builtin_bit_cast(bf16x8, *(const ushort8*)&As[ar * 72 + kk * 32 + (l >> 4) * 8]);
      }
      #pragma unroll
      for (int ni = 0; ni < 4; ++ni){
        const int br = wn * 64 + ni * 16 + (l & 15);
        bv[ni] = __builtin_bit_cast(bf16x8, *(const ushort8*)&Bs[br * 72 + kk * 32 + (l >> 4) * 8]);
      }
      #pragma unroll
      for (int mi = 0; mi < 4; ++mi)
        #pragma unroll
        for (int ni = 0; ni < 4; ++ni)
          acc[mi][ni] = __builtin_amdgcn_mfma_f32_16x16x32_bf16(av[mi], bv[ni], acc[mi][ni], 0, 0, 0);
    }
    __syncthreads();
  }
  #pragma unroll
  for (int mi = 0; mi < 4; ++mi){
    const int rowb = brow + wm * 64 + mi * 16 + (l >> 4) * 4;
    #pragma unroll
    for (int ni = 0; ni < 4; ++ni){
      const int col = bcol + wn * 64 + ni * 16 + (l & 15);
      #pragma unroll
      for (int rr = 0; rr < 4; ++rr)
        zp[(size_t)(rowb + rr) * N + col] = __half_as_ushort(__float2half(acc[mi][ni][rr]));
    }
  }
}

// ---------------------------------------------------------------------------
// fpass: per row i, online LSE_j(gt_j + 2 z_ij).  One wave per row.
// MODE 0: ft[i] = LOG_N - lse    (ft = f - x2 = -(logb + lse))
// MODE 1: final eval: r_i = exp(ft_i + lse - 2*LOG_N), contrib = (ft+x2)*r
// Group-of-8 max trick: 9 exps per 8 elements.
// ---------------------------------------------------------------------------
template<int MODE>
__global__ __launch_bounds__(256) void fpass_k(const u16* __restrict__ zp,
                                               const float* __restrict__ gt,
                                               float* ft,
                                               const float* __restrict__ x2,
                                               float* __restrict__ contrib){
  const int w = threadIdx.x >> 6, l = threadIdx.x & 63;
  const int i = blockIdx.x * 4 + w;
  const u16* zr = zp + (size_t)i * N;
  float m = -1e30f, s = 0.f;
  for (int it = 0; it < N / 512; ++it){
    const int c0 = it * 512 + l * 8;
    ushort8 zz = *(const ushort8*)(zr + c0);
    float4 ga = *(const float4*)(gt + c0);
    float4 gb = *(const float4*)(gt + c0 + 4);
    float t0 = __builtin_fmaf(2.f, h2f(zz[0]), ga.x);
    float t1 = __builtin_fmaf(2.f, h2f(zz[1]), ga.y);
    float t2 = __builtin_fmaf(2.f, h2f(zz[2]), ga.z);
    float t3 = __builtin_fmaf(2.f, h2f(zz[3]), ga.w);
    float t4 = __builtin_fmaf(2.f, h2f(zz[4]), gb.x);
    float t5 = __builtin_fmaf(2.f, h2f(zz[5]), gb.y);
    float t6 = __builtin_fmaf(2.f, h2f(zz[6]), gb.z);
    float t7 = __builtin_fmaf(2.f, h2f(zz[7]), gb.w);
    float gm = fmaxf(fmaxf(fmaxf(t0, t1), fmaxf(t2, t3)),
                     fmaxf(fmaxf(t4, t5), fmaxf(t6, t7)));
    float nm = fmaxf(m, gm);
    float sum = __expf(t0 - nm) + __expf(t1 - nm) + __expf(t2 - nm) + __expf(t3 - nm)
              + __expf(t4 - nm) + __expf(t5 - nm) + __expf(t6 - nm) + __expf(t7 - nm);
    s = __builtin_fmaf(s, __expf(m - nm), sum);
    m = nm;
  }
  #pragma unroll
  for (int off = 32; off > 0; off >>= 1){
    float om = __shfl_down(m, off);
    float os = __shfl_down(s, off);
    float nm = fmaxf(m, om);
    s = __builtin_fmaf(s, __expf(m - nm), os * __expf(om - nm));
    m = nm;
  }
  if (l == 0){
    float lse = m + __logf(s);
    if (MODE == 0){
      ft[i] = LOG_N - lse;
    } else {
      float fti = ft[i];
      float r = __expf(fti + lse - 2.f * LOG_N);
      contrib[i] = (fti + x2[i]) * r;
    }
  }
}

// ---------------------------------------------------------------------------
// gpass: column online LSE_i(ft_i + 2 z_ij), two-stage.  Each thread owns 8
// consecutive columns; block covers 2048 cols x 64-row chunk. Grid (4,128).
// ---------------------------------------------------------------------------
__global__ __launch_bounds__(256) void gpass_k(const u16* __restrict__ zp,
                                               const float* __restrict__ ft,
                                               float* __restrict__ pm,
                                               float* __restrict__ ps){
  const int c0 = blockIdx.x * 2048 + threadIdx.x * 8;
  const int r0base = blockIdx.y * 64;
  float m[8], s[8];
  #pragma unroll
  for (int e = 0; e < 8; ++e){ m[e] = -1e30f; s[e] = 0.f; }
  for (int rg = 0; rg < 8; ++rg){
    const int r0 = r0base + rg * 8;
    float t[8][8];
    #pragma unroll
    for (int r = 0; r < 8; ++r){
      const float fv = ft[r0 + r];           // uniform -> scalar load
      ushort8 zz = *(const ushort8*)(zp + (size_t)(r0 + r) * N + c0);
      #pragma unroll
      for (int e = 0; e < 8; ++e) t[r][e] = __builtin_fmaf(2.f, h2f(zz[e]), fv);
    }
    #pragma unroll
    for (int e = 0; e < 8; ++e){
      float gm = t[0][e];
      #pragma unroll
      for (int r = 1; r < 8; ++r) gm = fmaxf(gm, t[r][e]);
      float nm = fmaxf(m[e], gm);
      float sum = 0.f;
      #pragma unroll
      for (int r = 0; r < 8; ++r) sum += __expf(t[r][e] - nm);
      s[e] = __builtin_fmaf(s[e], __expf(m[e] - nm), sum);
      m[e] = nm;
    }
  }
  const size_t pb = (size_t)blockIdx.y * N + c0;
  #pragma unroll
  for (int e = 0; e < 8; e += 4){
    *(float4*)(pm + pb + e) = make_float4(m[e], m[e+1], m[e+2], m[e+3]);
    *(float4*)(ps + pb + e) = make_float4(s[e], s[e+1], s[e+2], s[e+3]);
  }
}

__global__ __launch_bounds__(256) void gmerge_k(const float* __restrict__ pm,
                                                const float* __restrict__ ps,
                                                float* __restrict__ gt){
  const int j = blockIdx.x * 256 + threadIdx.x;
  float m = -1e30f, s = 0.f;
  for (int ch = 0; ch < 128; ++ch){
    float om = pm[(size_t)ch * N + j];
    float os = ps[(size_t)ch * N + j];
    float nm = fmaxf(m, om);
    s = __builtin_fmaf(s, __expf(m - nm), os * __expf(om - nm));
    m = nm;
  }
  gt[j] = LOG_N - (m + __logf(s));   // gt = -(loga + lse)
}

// ---------------------------------------------------------------------------
// finish: value = sum(contrib) + mean_j(gt_j + y2_j);  out = sqrt(value)
// ---------------------------------------------------------------------------
__global__ __launch_bounds__(256) void finish_k(const float* __restrict__ contrib,
                                                const float* __restrict__ gt,
                                                const float* __restrict__ y2,
                                                float* __restrict__ out){
  __shared__ float s1[256], s2[256];
  const int t = threadIdx.x;
  float a = 0.f, b = 0.f;
  for (int j = t; j < N; j += 256){ a += contrib[j]; b += gt[j] + y2[j]; }
  s1[t] = a; s2[t] = b; __syncthreads();
  for (int st = 128; st > 0; st >>= 1){
    if (t < st){ s1[t] += s1[t + st]; s2[t] += s2[t + st]; }
    __syncthreads();
  }
  if (t == 0) out[0] = sqrtf(s1[0] + s2[0] * (1.0f / (float)N));
}

// ---------------------------------------------------------------------------
extern "C" void kernel_launch(void* const* d_in, const int* in_sizes, int n_in,
                              void* d_out, int out_size, void* d_ws, size_t ws_size,
                              hipStream_t stream){
  const float* x = (const float*)d_in[0];
  const float* y = (const float*)d_in[1];
  float* out = (float*)d_out;
  char* ws = (char*)d_ws;

  // workspace layout (bytes)
  u16*   zp      = (u16*)  (ws);                 // fp16 z, 8192*8192*2 = 128 MiB
  u16*   xb      = (u16*)  (ws + 134217728);     // bf16 x, 4 MiB
  u16*   yb      = (u16*)  (ws + 138412032);     // bf16 y, 4 MiB
  float* x2      = (float*)(ws + 142606336);     // 32 KiB
  float* y2      = (float*)(ws + 142639104);
  float* ft      = (float*)(ws + 142671872);
  float* gt      = (float*)(ws + 142704640);
  float* contrib = (float*)(ws + 142737408);
  float* pm      = (float*)(ws + 142770176);     // 128*8192*4 = 4 MiB
  float* ps      = (float*)(ws + 146964480);     // 4 MiB  (end ~151.2 MB)

  prep_k<<<4096, 256, 0, stream>>>(x, y, xb, yb, x2, y2, gt);
  gemm_k<<<dim3(64, 64), 256, 0, stream>>>(xb, yb, zp);
  for (int it = 0; it < 50; ++it){
    fpass_k<0><<<2048, 256, 0, stream>>>(zp, gt, ft, x2, contrib);
    gpass_k<<<dim3(4, 128), 256, 0, stream>>>(zp, ft, pm, ps);
    gmerge_k<<<32, 256, 0, stream>>>(pm, ps, gt);
  }
  fpass_k<1><<<2048, 256, 0, stream>>>(zp, gt, ft, x2, contrib);
  finish_k<<<1, 256, 0, stream>>>(contrib, gt, y2, out);
}

// Round 2
// 2719.312 us; speedup vs baseline: 1.3104x; 1.3104x over previous
//
#include <hip/hip_runtime.h>
#include <hip/hip_fp16.h>

#define N 8192
#define DK 256
#define LOG2E 1.4426950408889634f
#define LN2   0.6931471805599453f
// log2(8192) = 13 exactly; loga+logb in log2 units = -26

typedef unsigned short u16;
typedef u16   ushort8 __attribute__((ext_vector_type(8)));
typedef u16   u16x4   __attribute__((ext_vector_type(4)));
typedef __bf16 bf16x8 __attribute__((ext_vector_type(8)));
typedef float  f32x4  __attribute__((ext_vector_type(4)));

__device__ __forceinline__ u16 f2bf(float f){
  unsigned u = __builtin_bit_cast(unsigned, f);
  return (u16)((u + 0x7fffu + ((u >> 16) & 1u)) >> 16);   // RNE fp32->bf16
}
__device__ __forceinline__ float ex2(float x){            // v_exp_f32 = 2^x
  float r; asm("v_exp_f32 %0, %1" : "=v"(r) : "v"(x)); return r;
}
__device__ __forceinline__ float lg2(float x){            // v_log_f32 = log2(x)
  float r; asm("v_log_f32 %0, %1" : "=v"(r) : "v"(x)); return r;
}
__device__ __forceinline__ float2 cvt2(u16 a, u16 b){
  __half2 h;
  h.x = __ushort_as_half(a); h.y = __ushort_as_half(b);
  return __half22float2(h);
}

// ---------------------------------------------------------------------------
// prep: row sum-of-squares + bf16 copies + init GtL = -y2*log2e  (g0 = 0)
// ---------------------------------------------------------------------------
__global__ __launch_bounds__(256) void prep_k(const float* __restrict__ x, const float* __restrict__ y,
                                              u16* __restrict__ xb, u16* __restrict__ yb,
                                              float* __restrict__ x2, float* __restrict__ y2,
                                              float* __restrict__ gt){
  const int w = threadIdx.x >> 6, l = threadIdx.x & 63;
  const int r = blockIdx.x * 4 + w;         // 0..16383
  const bool isx = r < N;
  const int rr = isx ? r : r - N;
  const float* src = (isx ? x : y) + (size_t)rr * DK;
  float4 v = *(const float4*)(src + l * 4);
  ushort4 bv;
  bv.x = f2bf(v.x); bv.y = f2bf(v.y); bv.z = f2bf(v.z); bv.w = f2bf(v.w);
  *(ushort4*)((isx ? xb : yb) + (size_t)rr * DK + l * 4) = bv;
  float p = v.x*v.x + v.y*v.y + v.z*v.z + v.w*v.w;
  #pragma unroll
  for (int off = 32; off > 0; off >>= 1) p += __shfl_down(p, off);
  if (l == 0){
    if (isx) x2[rr] = p;
    else { y2[rr] = p; gt[rr] = -p * LOG2E; }
  }
}

// ---------------------------------------------------------------------------
// gemm: z = xb * yb^T (bf16 MFMA), store Zl = 2*log2e*z as fp16.
// ---------------------------------------------------------------------------
__global__ __launch_bounds__(256) void gemm_k(const u16* __restrict__ xb, const u16* __restrict__ yb,
                                              u16* __restrict__ zp){
  __shared__ u16 As[128 * 72];
  __shared__ u16 Bs[128 * 72];
  const int t = threadIdx.x;
  const int w = t >> 6, l = t & 63;
  const int wm = w >> 1, wn = w & 1;
  const int brow = blockIdx.y * 128, bcol = blockIdx.x * 128;
  const int tr = t >> 3, tc = t & 7;
  f32x4 acc[4][4] = {};
  for (int ks = 0; ks < 4; ++ks){
    #pragma unroll
    for (int rr = 0; rr < 4; ++rr){
      const int row = tr + rr * 32;
      *(ushort8*)&As[row * 72 + tc * 8] = *(const ushort8*)&xb[(size_t)(brow + row) * DK + ks * 64 + tc * 8];
      *(ushort8*)&Bs[row * 72 + tc * 8] = *(const ushort8*)&yb[(size_t)(bcol + row) * DK + ks * 64 + tc * 8];
    }
    __syncthreads();
    #pragma unroll
    for (int kk = 0; kk < 2; ++kk){
      bf16x8 av[4], bv[4];
      #pragma unroll
      for (int mi = 0; mi < 4; ++mi){
        const int ar = wm * 64 + mi * 16 + (l & 15);
        av[mi] = __builtin_bit_cast(bf16x8, *(const ushort8*)&As[ar * 72 + kk * 32 + (l >> 4) * 8]);
      }
      #pragma unroll
      for (int ni = 0; ni < 4; ++ni){
        const int br = wn * 64 + ni * 16 + (l & 15);
        bv[ni] = __builtin_bit_cast(bf16x8, *(const ushort8*)&Bs[br * 72 + kk * 32 + (l >> 4) * 8]);
      }
      #pragma unroll
      for (int mi = 0; mi < 4; ++mi)
        #pragma unroll
        for (int ni = 0; ni < 4; ++ni)
          acc[mi][ni] = __builtin_amdgcn_mfma_f32_16x16x32_bf16(av[mi], bv[ni], acc[mi][ni], 0, 0, 0);
    }
    __syncthreads();
  }
  #pragma unroll
  for (int mi = 0; mi < 4; ++mi){
    const int rowb = brow + wm * 64 + mi * 16 + (l >> 4) * 4;
    #pragma unroll
    for (int ni = 0; ni < 4; ++ni){
      const int col = bcol + wn * 64 + ni * 16 + (l & 15);
      #pragma unroll
      for (int rr = 0; rr < 4; ++rr)
        zp[(size_t)(rowb + rr) * N + col] = __half_as_ushort(__float2half(acc[mi][ni][rr] * 2.8853901f));
    }
  }
}

// ---------------------------------------------------------------------------
// fpass: per row i, online log2-LSE_j(GtL_j + Zl_ij).  One wave per row.
// MODE 0: FtL[i] = 13 - lse2
// MODE 1: r_i = 2^(FtL_i + lse2 - 26); contrib = (FtL*ln2 + x2)*r
// Group-of-8 max (max3-fused), depth-2 prefetch, fully unrolled.
// ---------------------------------------------------------------------------
template<int MODE>
__global__ __launch_bounds__(256) void fpass_k(const u16* __restrict__ zp,
                                               const float* __restrict__ gt,
                                               float* ft,
                                               const float* __restrict__ x2,
                                               float* __restrict__ contrib){
  const int w = threadIdx.x >> 6, l = threadIdx.x & 63;
  const int i = blockIdx.x * 4 + w;
  const u16* zr = zp + (size_t)i * N + l * 8;
  float m = -1e30f, s = 0.f;
  ushort8 zA = *(const ushort8*)(zr);
  ushort8 zB = *(const ushort8*)(zr + 512);
  #pragma unroll
  for (int it = 0; it < 16; ++it){
    ushort8 zC = {};
    if (it < 14) zC = *(const ushort8*)(zr + (it + 2) * 512);
    const float4 ga = *(const float4*)(gt + it * 512 + l * 8);
    const float4 gb = *(const float4*)(gt + it * 512 + l * 8 + 4);
    float2 c0 = cvt2(zA[0], zA[1]), c1 = cvt2(zA[2], zA[3]);
    float2 c2 = cvt2(zA[4], zA[5]), c3 = cvt2(zA[6], zA[7]);
    float t0 = c0.x + ga.x, t1 = c0.y + ga.y, t2 = c1.x + ga.z, t3 = c1.y + ga.w;
    float t4 = c2.x + gb.x, t5 = c2.y + gb.y, t6 = c3.x + gb.z, t7 = c3.y + gb.w;
    // serial chain -> v_max3 fusion (4 instrs), includes running m
    float nm = fmaxf(m, t0); nm = fmaxf(nm, t1); nm = fmaxf(nm, t2); nm = fmaxf(nm, t3);
    nm = fmaxf(nm, t4); nm = fmaxf(nm, t5); nm = fmaxf(nm, t6); nm = fmaxf(nm, t7);
    float sum = ex2(t0 - nm) + ex2(t1 - nm) + ex2(t2 - nm) + ex2(t3 - nm)
              + ex2(t4 - nm) + ex2(t5 - nm) + ex2(t6 - nm) + ex2(t7 - nm);
    s = __builtin_fmaf(s, ex2(m - nm), sum);
    m = nm;
    zA = zB; zB = zC;
  }
  #pragma unroll
  for (int off = 32; off > 0; off >>= 1){
    float om = __shfl_down(m, off);
    float os = __shfl_down(s, off);
    float nm = fmaxf(m, om);
    s = __builtin_fmaf(s, ex2(m - nm), os * ex2(om - nm));
    m = nm;
  }
  if (l == 0){
    float lse2 = m + lg2(s);
    if (MODE == 0){
      ft[i] = 13.0f - lse2;
    } else {
      float fti = ft[i];
      float r = ex2(fti + lse2 - 26.0f);
      contrib[i] = (fti * LN2 + x2[i]) * r;
    }
  }
}

// ---------------------------------------------------------------------------
// gpass: column log2-LSE_i(FtL_i + Zl_ij), two-stage. 4 cols/thread,
// 128 rows/block.  Grid (8, 64).
// ---------------------------------------------------------------------------
__global__ __launch_bounds__(256) void gpass_k(const u16* __restrict__ zp,
                                               const float* __restrict__ ft,
                                               float* __restrict__ pm,
                                               float* __restrict__ ps){
  const int c0 = blockIdx.x * 1024 + threadIdx.x * 4;
  const int r0base = blockIdx.y * 128;
  float m[4], s[4];
  #pragma unroll
  for (int e = 0; e < 4; ++e){ m[e] = -1e30f; s[e] = 0.f; }
  for (int rg = 0; rg < 16; ++rg){
    const int r0 = r0base + rg * 8;
    float t[8][4];
    #pragma unroll
    for (int r = 0; r < 8; ++r){
      const float fv = ft[r0 + r];           // uniform -> scalar load
      u16x4 zz = *(const u16x4*)(zp + (size_t)(r0 + r) * N + c0);
      float2 a = cvt2(zz[0], zz[1]), b = cvt2(zz[2], zz[3]);
      t[r][0] = a.x + fv; t[r][1] = a.y + fv; t[r][2] = b.x + fv; t[r][3] = b.y + fv;
    }
    #pragma unroll
    for (int e = 0; e < 4; ++e){
      float nm = fmaxf(m[e], t[0][e]);
      #pragma unroll
      for (int r = 1; r < 8; ++r) nm = fmaxf(nm, t[r][e]);
      float sum = 0.f;
      #pragma unroll
      for (int r = 0; r < 8; ++r) sum += ex2(t[r][e] - nm);
      s[e] = __builtin_fmaf(s[e], ex2(m[e] - nm), sum);
      m[e] = nm;
    }
  }
  const size_t pb = (size_t)blockIdx.y * N + c0;
  *(float4*)(pm + pb) = make_float4(m[0], m[1], m[2], m[3]);
  *(float4*)(ps + pb) = make_float4(s[0], s[1], s[2], s[3]);
}

__global__ __launch_bounds__(256) void gmerge_k(const float* __restrict__ pm,
                                                const float* __restrict__ ps,
                                                float* __restrict__ gt){
  const int j = blockIdx.x * 256 + threadIdx.x;
  float m = -1e30f, s = 0.f;
  for (int ch = 0; ch < 64; ++ch){
    float om = pm[(size_t)ch * N + j];
    float os = ps[(size_t)ch * N + j];
    float nm = fmaxf(m, om);
    s = __builtin_fmaf(s, ex2(m - nm), os * ex2(om - nm));
    m = nm;
  }
  gt[j] = 13.0f - (m + lg2(s));   // GtL = -(loga + lse) in log2 units
}

// ---------------------------------------------------------------------------
// finish: value = sum(contrib) + mean_j(GtL_j*ln2 + y2_j);  out = sqrt(value)
// ---------------------------------------------------------------------------
__global__ __launch_bounds__(256) void finish_k(const float* __restrict__ contrib,
                                                const float* __restrict__ gt,
                                                const float* __restrict__ y2,
                                                float* __restrict__ out){
  __shared__ float s1[256], s2[256];
  const int t = threadIdx.x;
  float a = 0.f, b = 0.f;
  for (int j = t; j < N; j += 256){ a += contrib[j]; b += gt[j] * LN2 + y2[j]; }
  s1[t] = a; s2[t] = b; __syncthreads();
  for (int st = 128; st > 0; st >>= 1){
    if (t < st){ s1[t] += s1[t + st]; s2[t] += s2[t + st]; }
    __syncthreads();
  }
  if (t == 0) out[0] = sqrtf(s1[0] + s2[0] * (1.0f / (float)N));
}

// ---------------------------------------------------------------------------
extern "C" void kernel_launch(void* const* d_in, const int* in_sizes, int n_in,
                              void* d_out, int out_size, void* d_ws, size_t ws_size,
                              hipStream_t stream){
  const float* x = (const float*)d_in[0];
  const float* y = (const float*)d_in[1];
  float* out = (float*)d_out;
  char* ws = (char*)d_ws;

  // workspace layout (bytes)
  u16*   zp      = (u16*)  (ws);                 // fp16 Zl, 128 MiB
  u16*   xb      = (u16*)  (ws + 134217728);     // bf16 x, 4 MiB
  u16*   yb      = (u16*)  (ws + 138412032);     // bf16 y, 4 MiB
  float* x2      = (float*)(ws + 142606336);
  float* y2      = (float*)(ws + 142639104);
  float* ft      = (float*)(ws + 142671872);
  float* gt      = (float*)(ws + 142704640);
  float* contrib = (float*)(ws + 142737408);
  float* pm      = (float*)(ws + 142770176);     // 64*8192*4 = 2 MiB
  float* ps      = (float*)(ws + 146964480);     // 2 MiB

  prep_k<<<4096, 256, 0, stream>>>(x, y, xb, yb, x2, y2, gt);
  gemm_k<<<dim3(64, 64), 256, 0, stream>>>(xb, yb, zp);
  for (int it = 0; it < 50; ++it){
    fpass_k<0><<<2048, 256, 0, stream>>>(zp, gt, ft, x2, contrib);
    gpass_k<<<dim3(8, 64), 256, 0, stream>>>(zp, ft, pm, ps);
    gmerge_k<<<32, 256, 0, stream>>>(pm, ps, gt);
  }
  fpass_k<1><<<2048, 256, 0, stream>>>(zp, gt, ft, x2, contrib);
  finish_k<<<1, 256, 0, stream>>>(contrib, gt, y2, out);
}